// Round 1
// baseline (849.152 us; speedup 1.0000x reference)
//
#include <hip/hip_runtime.h>
#include <hip/hip_bf16.h>
#include <cstddef>

// ---- problem constants ----
#define Bc   2
#define Lc   8192
#define TGT  6146          // L - RF, RF = 2046
#define NL   20            // layers
#define RCc  32
#define DCc  32
#define SCc  1024
#define ECc  512
#define OCc  256

// ============================================================
// K0: input 1x1 conv  (B,256,L) x (32,256) -> res (B,32,L)
// block: 256 thr = 64 time positions x 4 oc-groups(8 oc each)
// ============================================================
__global__ __launch_bounds__(256) void input_conv(
    const float* __restrict__ x,   // [B][256][L]
    const float* __restrict__ w,   // [32][256]
    float* __restrict__ res_out)   // [B][32][L]
{
    __shared__ float ws[32][256];  // 32KB
    __shared__ float xs[64][64];   // 16KB (ic chunk x time)
    int tid = threadIdx.x;
    int b   = blockIdx.y;
    int t0  = blockIdx.x * 64;

    for (int idx = tid; idx < 32 * 256; idx += 256)
        ws[idx >> 8][idx & 255] = w[idx];

    int tl = tid & 63, q = tid >> 6, oc0 = q * 8;
    float acc[8] = {};

    for (int icc = 0; icc < 4; ++icc) {
        __syncthreads();
        for (int idx = tid; idx < 64 * 64; idx += 256) {
            int icl = idx >> 6, tll = idx & 63;
            xs[icl][tll] = x[((size_t)b * 256 + icc * 64 + icl) * Lc + t0 + tll];
        }
        __syncthreads();
        for (int icl = 0; icl < 64; icl += 4) {
            float x0 = xs[icl][tl], x1 = xs[icl + 1][tl];
            float x2 = xs[icl + 2][tl], x3 = xs[icl + 3][tl];
#pragma unroll
            for (int j = 0; j < 8; ++j) {
                const float4 w4 = *(const float4*)&ws[oc0 + j][icc * 64 + icl];
                acc[j] += w4.x * x0 + w4.y * x1 + w4.z * x2 + w4.w * x3;
            }
        }
    }
#pragma unroll
    for (int j = 0; j < 8; ++j)
        res_out[((size_t)b * 32 + oc0 + j) * Lc + t0 + tl] = acc[j];
}

// ============================================================
// per-layer kernel: dilated K=2 gated conv + residual + skip-out
// block: 256 thr = 64 time x 4 oc-groups(8 oc)
// ============================================================
__global__ __launch_bounds__(256) void layer_kernel(
    const float* __restrict__ res_in,   // [B][32][L]
    float* __restrict__ res_out,        // [B][32][L]
    float* __restrict__ outs_i,         // [32][B][TGT]   (k-major for GEMM)
    const float* __restrict__ filt,     // [32][32][2]
    const float* __restrict__ gate,     // [32][32][2]
    const float* __restrict__ resw,     // [32][32]
    const float* __restrict__ cond,     // [B][5]
    const float* __restrict__ gcf,      // [5]
    const float* __restrict__ gcs,      // [5]
    int dil)
{
    __shared__ float wfg[32][32][4];   // f0,f1,g0,g1   16KB
    __shared__ float wr[32][32];       // 4KB
    __shared__ float x0s[32][64];      // 8KB
    __shared__ float xms[32][64];      // 8KB
    __shared__ float osh[32][64];      // 8KB

    int tid = threadIdx.x;
    int b   = blockIdx.y;
    int t0  = blockIdx.x * 64;

    for (int idx = tid; idx < 32 * 32; idx += 256) {
        int oc = idx >> 5, ic = idx & 31;
        wfg[oc][ic][0] = filt[(oc * 32 + ic) * 2 + 0];
        wfg[oc][ic][1] = filt[(oc * 32 + ic) * 2 + 1];
        wfg[oc][ic][2] = gate[(oc * 32 + ic) * 2 + 0];
        wfg[oc][ic][3] = gate[(oc * 32 + ic) * 2 + 1];
        wr[oc][ic]     = resw[oc * 32 + ic];
    }
    for (int idx = tid; idx < 32 * 64; idx += 256) {
        int ic = idx >> 6, tll = idx & 63;
        int t = t0 + tll;
        x0s[ic][tll] = res_in[((size_t)b * 32 + ic) * Lc + t];
        int tm = t - dil;
        xms[ic][tll] = (tm >= 0) ? res_in[((size_t)b * 32 + ic) * Lc + tm] : 0.f;
    }
    __syncthreads();

    int tl = tid & 63, q = tid >> 6, oc0 = q * 8;

    float gcfv = 0.f, gcsv = 0.f;
    for (int c = 0; c < 5; ++c) {
        gcfv += cond[b * 5 + c] * gcf[c];
        gcsv += cond[b * 5 + c] * gcs[c];
    }
    float facc[8], gacc[8];
#pragma unroll
    for (int j = 0; j < 8; ++j) { facc[j] = gcfv; gacc[j] = gcsv; }

    for (int ic = 0; ic < 32; ++ic) {
        float xm = xms[ic][tl];
        float x0 = x0s[ic][tl];
#pragma unroll
        for (int j = 0; j < 8; ++j) {
            const float4 w4 = *(const float4*)&wfg[oc0 + j][ic][0];
            facc[j] += w4.x * xm + w4.y * x0;
            gacc[j] += w4.z * xm + w4.w * x0;
        }
    }

    float o[8];
#pragma unroll
    for (int j = 0; j < 8; ++j) {
        float f = facc[j], g = gacc[j];
        float th = 1.f - 2.f / (expf(2.f * f) + 1.f);   // tanh
        float sg = 1.f / (1.f + expf(-g));              // sigmoid
        o[j] = th * sg;
        osh[oc0 + j][tl] = o[j];
    }
    __syncthreads();

    float racc[8];
#pragma unroll
    for (int j = 0; j < 8; ++j) racc[j] = x0s[oc0 + j][tl];
    for (int ic = 0; ic < 32; ++ic) {
        float ov = osh[ic][tl];
#pragma unroll
        for (int j = 0; j < 8; ++j) racc[j] += wr[oc0 + j][ic] * ov;
    }

    int t = t0 + tl;
#pragma unroll
    for (int j = 0; j < 8; ++j)
        res_out[((size_t)b * 32 + oc0 + j) * Lc + t] = racc[j];

    if (t >= Lc - TGT) {
        int ts = t - (Lc - TGT);
#pragma unroll
        for (int j = 0; j < 8; ++j)
            outs_i[((size_t)(oc0 + j) * Bc + b) * TGT + ts] = o[j];
    }
}

// ============================================================
// repack split_w (nl,SC,DC) -> Apack[m=SC][k=nl*DC]
// ============================================================
__global__ void repack_split(const float* __restrict__ sw, float* __restrict__ Apack)
{
    int idx = blockIdx.x * 256 + threadIdx.x;
    if (idx >= SCc * (NL * DCc)) return;
    int m = idx / (NL * DCc), k = idx % (NL * DCc);
    int i = k >> 5, c = k & 31;
    Apack[idx] = sw[((size_t)i * SCc + m) * DCc + c];
}

// ============================================================
// fp32 tiled GEMM: C[b] = A(MxK) * B[b](KxN) (+bias) (opt relus)
// 64x64 tile, 256 thr, 4x4 micro
// B row k base = B + b*bstride + k*ldB
// ============================================================
template <bool RELU_IN, bool RELU_OUT, bool TRANS_OUT>
__global__ __launch_bounds__(256) void gemm_kernel(
    const float* __restrict__ A,
    const float* __restrict__ Bm,
    const float* __restrict__ bias,
    float* __restrict__ C,
    int M, int N, int K,
    int ldB, size_t bstride, size_t cstride)
{
    __shared__ float As[16][68];
    __shared__ float Bs[16][68];

    int b  = blockIdx.z;
    const float* Bb = Bm + (size_t)b * bstride;
    int m0 = blockIdx.x * 64, n0 = blockIdx.y * 64;
    int tid = threadIdx.x;
    int tm = tid & 15, tn = tid >> 4;

    float acc[4][4] = {};

    for (int k0 = 0; k0 < K; k0 += 16) {
        {   // A tile: As[k][m]
            int k = tid & 15, m = tid >> 4;
#pragma unroll
            for (int mm = 0; mm < 4; ++mm)
                As[k][m + mm * 16] = A[(size_t)(m0 + m + mm * 16) * K + k0 + k];
        }
        {   // B tile: Bs[k][n]
            int n = tid & 63, k4 = tid >> 6;
            int n_g = n0 + n;
#pragma unroll
            for (int kk = 0; kk < 4; ++kk) {
                int k = k4 * 4 + kk;
                float v = (n_g < N) ? Bb[(size_t)(k0 + k) * ldB + n_g] : 0.f;
                if (RELU_IN) v = fmaxf(v, 0.f);
                Bs[k][n] = v;
            }
        }
        __syncthreads();
#pragma unroll
        for (int k = 0; k < 16; ++k) {
            float a_[4], b_[4];
#pragma unroll
            for (int i = 0; i < 4; ++i) a_[i] = As[k][tm * 4 + i];
#pragma unroll
            for (int i = 0; i < 4; ++i) b_[i] = Bs[k][tn * 4 + i];
#pragma unroll
            for (int i = 0; i < 4; ++i)
#pragma unroll
                for (int j = 0; j < 4; ++j)
                    acc[i][j] += a_[i] * b_[j];
        }
        __syncthreads();
    }

#pragma unroll
    for (int i = 0; i < 4; ++i) {
        int m = m0 + tm * 4 + i;
        float bv = bias ? bias[m] : 0.f;
#pragma unroll
        for (int j = 0; j < 4; ++j) {
            int n = n0 + tn * 4 + j;
            if (n >= N) continue;
            float v = acc[i][j] + bv;
            if (RELU_OUT) v = fmaxf(v, 0.f);
            if (TRANS_OUT)
                C[((size_t)b * N + n) * M + m] = v;
            else
                C[(size_t)b * cstride + (size_t)m * N + n] = v;
        }
    }
}

// ============================================================
extern "C" void kernel_launch(void* const* d_in, const int* in_sizes, int n_in,
                              void* d_out, int out_size, void* d_ws, size_t ws_size,
                              hipStream_t stream)
{
    const float* inputs   = (const float*)d_in[0];
    const float* cond     = (const float*)d_in[1];
    const float* input_w  = (const float*)d_in[2];
    const float* filter_w = (const float*)d_in[3];
    const float* gate_w   = (const float*)d_in[4];
    const float* res_w    = (const float*)d_in[5];
    const float* split_w  = (const float*)d_in[6];
    const float* gcf_w    = (const float*)d_in[7];
    const float* gcs_w    = (const float*)d_in[8];
    const float* f1_w     = (const float*)d_in[9];
    const float* f1_b     = (const float*)d_in[10];
    const float* f2_w     = (const float*)d_in[11];
    const float* f2_b     = (const float*)d_in[12];
    float* out = (float*)d_out;

    float* ws = (float*)d_ws;
    const size_t RES_SZ  = (size_t)Bc * RCc * Lc;          // 524288
    const size_t OUTS_SZ = (size_t)NL * DCc * Bc * TGT;    // 7,866,880
    const size_t FIN_SZ  = (size_t)Bc * SCc * TGT;         // 12,587,008
    const size_t H1_SZ   = (size_t)Bc * ECc * TGT;         // 6,293,504
    const size_t AP_SZ   = (size_t)SCc * NL * DCc;         // 655,360

    float* res0   = ws;
    float* res1   = res0 + RES_SZ;
    float* outs   = res1 + RES_SZ;
    float* final_ = outs + OUTS_SZ;
    float* h1     = final_ + FIN_SZ;
    float* Apack  = h1 + H1_SZ;
    // total ~113.8 MB of ws

    input_conv<<<dim3(Lc / 64, Bc), 256, 0, stream>>>(inputs, input_w, res0);

    float* rin = res0;
    float* rout = res1;
    for (int i = 0; i < NL; ++i) {
        int d = 1 << (i % 10);
        layer_kernel<<<dim3(Lc / 64, Bc), 256, 0, stream>>>(
            rin, rout,
            outs + (size_t)i * DCc * Bc * TGT,
            filter_w + (size_t)i * DCc * RCc * 2,
            gate_w   + (size_t)i * DCc * RCc * 2,
            res_w    + (size_t)i * RCc * DCc,
            cond,
            gcf_w + i * 5,
            gcs_w + i * 5,
            d);
        float* tmp = rin; rin = rout; rout = tmp;
    }

    repack_split<<<(SCc * NL * DCc + 255) / 256, 256, 0, stream>>>(split_w, Apack);

    const int NT = (TGT + 63) / 64;  // 97
    // G1: final = Apack(1024x640) @ outs   (k rows stride 2*TGT, batch offset TGT)
    gemm_kernel<false, false, false><<<dim3(SCc / 64, NT, Bc), 256, 0, stream>>>(
        Apack, outs, nullptr, final_,
        SCc, TGT, NL * DCc, Bc * TGT, (size_t)TGT, (size_t)SCc * TGT);

    // G2: h1 = relu(f1_w(512x1024) @ relu(final) + f1_b)
    gemm_kernel<true, true, false><<<dim3(ECc / 64, NT, Bc), 256, 0, stream>>>(
        f1_w, final_, f1_b, h1,
        ECc, TGT, SCc, TGT, (size_t)SCc * TGT, (size_t)ECc * TGT);

    // G3: out[(b*TGT+n)*256+m] = f2_w(256x512) @ h1 + f2_b
    gemm_kernel<false, false, true><<<dim3(OCc / 64, NT, Bc), 256, 0, stream>>>(
        f2_w, h1, f2_b, out,
        OCc, TGT, ECc, TGT, (size_t)ECc * TGT, 0);
}

// Round 2
// 402.767 us; speedup vs baseline: 2.1083x; 2.1083x over previous
//
#include <hip/hip_runtime.h>
#include <hip/hip_bf16.h>
#include <cstddef>

// ---- problem constants ----
#define Bc   2
#define Lc   8192
#define TGT  6146          // L - RF, RF = 2046
#define NL   20            // layers
#define RCc  32
#define DCc  32
#define SCc  1024
#define ECc  512
#define OCc  256
#define KTOT (NL * DCc)    // 640
#define TTILES 49          // ceil(TGT/128)

typedef __attribute__((ext_vector_type(4))) float f32x4;
typedef __attribute__((ext_vector_type(8))) short bf16x8;
typedef __attribute__((ext_vector_type(4))) int i32x4;

// ============================================================
// K0: input 1x1 conv  (B,256,L) x (32,256) -> res (B,32,L)
// ============================================================
__global__ __launch_bounds__(256) void input_conv(
    const float* __restrict__ x,   // [B][256][L]
    const float* __restrict__ w,   // [32][256]
    float* __restrict__ res_out)   // [B][32][L]
{
    __shared__ float ws[32][256];
    __shared__ float xs[64][64];
    int tid = threadIdx.x;
    int b   = blockIdx.y;
    int t0  = blockIdx.x * 64;

    for (int idx = tid; idx < 32 * 256; idx += 256)
        ws[idx >> 8][idx & 255] = w[idx];

    int tl = tid & 63, qq = tid >> 6, oc0 = qq * 8;
    float acc[8] = {};

    for (int icc = 0; icc < 4; ++icc) {
        __syncthreads();
        for (int idx = tid; idx < 64 * 64; idx += 256) {
            int icl = idx >> 6, tll = idx & 63;
            xs[icl][tll] = x[((size_t)b * 256 + icc * 64 + icl) * Lc + t0 + tll];
        }
        __syncthreads();
        for (int icl = 0; icl < 64; icl += 4) {
            float x0 = xs[icl][tl], x1 = xs[icl + 1][tl];
            float x2 = xs[icl + 2][tl], x3 = xs[icl + 3][tl];
#pragma unroll
            for (int j = 0; j < 8; ++j) {
                const float4 w4 = *(const float4*)&ws[oc0 + j][icc * 64 + icl];
                acc[j] += w4.x * x0 + w4.y * x1 + w4.z * x2 + w4.w * x3;
            }
        }
    }
#pragma unroll
    for (int j = 0; j < 8; ++j)
        res_out[((size_t)b * 32 + oc0 + j) * Lc + t0 + tl] = acc[j];
}

// ============================================================
// per-layer: dilated K=2 gated conv + residual; gated output o
// stored bf16 time-major into outsT[b*TGT+t][li*32+ch]
// ============================================================
__global__ __launch_bounds__(256) void layer_kernel(
    const float* __restrict__ res_in,   // [B][32][L]
    float* __restrict__ res_out,        // [B][32][L]
    __hip_bfloat16* __restrict__ outsT, // [B*TGT][640]
    const float* __restrict__ filt,
    const float* __restrict__ gate,
    const float* __restrict__ resw,
    const float* __restrict__ cond,
    const float* __restrict__ gcf,
    const float* __restrict__ gcs,
    int dil, int li)
{
    __shared__ float wfg[32][32][4];
    __shared__ float wr[32][32];
    __shared__ float x0s[32][64];
    __shared__ float xms[32][64];
    __shared__ float osh[32][64];

    int tid = threadIdx.x;
    int b   = blockIdx.y;
    int t0  = blockIdx.x * 64;

    for (int idx = tid; idx < 32 * 32; idx += 256) {
        int oc = idx >> 5, ic = idx & 31;
        wfg[oc][ic][0] = filt[(oc * 32 + ic) * 2 + 0];
        wfg[oc][ic][1] = filt[(oc * 32 + ic) * 2 + 1];
        wfg[oc][ic][2] = gate[(oc * 32 + ic) * 2 + 0];
        wfg[oc][ic][3] = gate[(oc * 32 + ic) * 2 + 1];
        wr[oc][ic]     = resw[oc * 32 + ic];
    }
    for (int idx = tid; idx < 32 * 64; idx += 256) {
        int ic = idx >> 6, tll = idx & 63;
        int t = t0 + tll;
        x0s[ic][tll] = res_in[((size_t)b * 32 + ic) * Lc + t];
        int tm = t - dil;
        xms[ic][tll] = (tm >= 0) ? res_in[((size_t)b * 32 + ic) * Lc + tm] : 0.f;
    }
    __syncthreads();

    int tl = tid & 63, qq = tid >> 6, oc0 = qq * 8;

    float gcfv = 0.f, gcsv = 0.f;
    for (int c = 0; c < 5; ++c) {
        gcfv += cond[b * 5 + c] * gcf[c];
        gcsv += cond[b * 5 + c] * gcs[c];
    }
    float facc[8], gacc[8];
#pragma unroll
    for (int j = 0; j < 8; ++j) { facc[j] = gcfv; gacc[j] = gcsv; }

    for (int ic = 0; ic < 32; ++ic) {
        float xm = xms[ic][tl];
        float x0 = x0s[ic][tl];
#pragma unroll
        for (int j = 0; j < 8; ++j) {
            const float4 w4 = *(const float4*)&wfg[oc0 + j][ic][0];
            facc[j] += w4.x * xm + w4.y * x0;
            gacc[j] += w4.z * xm + w4.w * x0;
        }
    }

    float o[8];
#pragma unroll
    for (int j = 0; j < 8; ++j) {
        float f = facc[j], g = gacc[j];
        float th = 1.f - 2.f / (expf(2.f * f) + 1.f);   // tanh
        float sg = 1.f / (1.f + expf(-g));              // sigmoid
        o[j] = th * sg;
        osh[oc0 + j][tl] = o[j];
    }
    __syncthreads();

    float racc[8];
#pragma unroll
    for (int j = 0; j < 8; ++j) racc[j] = x0s[oc0 + j][tl];
    for (int ic = 0; ic < 32; ++ic) {
        float ov = osh[ic][tl];
#pragma unroll
        for (int j = 0; j < 8; ++j) racc[j] += wr[oc0 + j][ic] * ov;
    }

    int t = t0 + tl;
#pragma unroll
    for (int j = 0; j < 8; ++j)
        res_out[((size_t)b * 32 + oc0 + j) * Lc + t] = racc[j];

    if (t >= Lc - TGT) {
        int ts = t - (Lc - TGT);
        union { i32x4 v; __hip_bfloat16 h[8]; } u;
#pragma unroll
        for (int j = 0; j < 8; ++j) u.h[j] = __float2bfloat16(o[j]);
        *(i32x4*)(outsT + ((size_t)(b * TGT + ts)) * KTOT + li * 32 + oc0) = u.v;
    }
}

// ============================================================
// weight packs (fp32 -> bf16, [M][K] row-major)
// ============================================================
__global__ void pack_w1(const float* __restrict__ sw, __hip_bfloat16* __restrict__ d)
{
    int idx = blockIdx.x * 256 + threadIdx.x;
    if (idx >= SCc * KTOT) return;
    int m = idx / KTOT, k = idx % KTOT;
    int i = k >> 5, c = k & 31;
    d[idx] = __float2bfloat16(sw[((size_t)i * SCc + m) * DCc + c]);
}

__global__ void pack_plain(const float* __restrict__ s, __hip_bfloat16* __restrict__ d, int n)
{
    int idx = blockIdx.x * 256 + threadIdx.x;
    if (idx < n) d[idx] = __float2bfloat16(s[idx]);
}

// ============================================================
// bf16 MFMA GEMM: Y[t][m] = sum_k X[t][k] * W[m][k]  (+bias, relu)
// X: [2*TGT][K] bf16 (time-major), W: [M][K] bf16, Y: [2*TGT][M]
// block: 256 thr (4 waves 2x2), tile 128t x 128m, BK=64
// LDS XOR-swizzled on 16B granules: slot = row*8 + (g ^ (row&7))
// ============================================================
template <bool RELU_OUT, bool OUT_BF16>
__global__ __launch_bounds__(256) void gemm_mfma(
    const __hip_bfloat16* __restrict__ X,
    const __hip_bfloat16* __restrict__ W,
    const float* __restrict__ bias,
    void* __restrict__ Y,
    int M, int K)
{
    __shared__ i32x4 Xs[128 * 8];
    __shared__ i32x4 Ws[128 * 8];

    int tid = threadIdx.x;
    int m0  = blockIdx.x * 128;
    int by  = blockIdx.y;
    int b   = by / TTILES;
    int t0  = (by % TTILES) * 128;

    int lane = tid & 63, wid = tid >> 6;
    int wy = wid >> 1, wx = wid & 1;
    int r15 = lane & 15, q = lane >> 4;

    // staging map: thread -> row sr (0..127), half hf (granules 0-3 / 4-7)
    int sr = tid >> 1, hf = tid & 1;
    int xrow = t0 + sr; if (xrow > TGT - 1) xrow = TGT - 1;
    const i32x4* gx = (const i32x4*)(X + ((size_t)(b * TGT + xrow)) * K) + hf * 4;
    const i32x4* gw = (const i32x4*)(W + ((size_t)(m0 + sr)) * K) + hf * 4;
    int wslot[4];
#pragma unroll
    for (int g = 0; g < 4; ++g) wslot[g] = sr * 8 + ((hf * 4 + g) ^ (sr & 7));

    f32x4 acc[4][4] = {};

    i32x4 rx[4], rw[4];
#pragma unroll
    for (int g = 0; g < 4; ++g) { rx[g] = gx[g]; rw[g] = gw[g]; }

    const int nkt = K >> 6;
    for (int kt = 0; kt < nkt; ++kt) {
        __syncthreads();
#pragma unroll
        for (int g = 0; g < 4; ++g) { Xs[wslot[g]] = rx[g]; Ws[wslot[g]] = rw[g]; }
        __syncthreads();
        if (kt + 1 < nkt) {
            gx += 8; gw += 8;
#pragma unroll
            for (int g = 0; g < 4; ++g) { rx[g] = gx[g]; rw[g] = gw[g]; }
        }
        const bf16x8* Xv = (const bf16x8*)Xs;
        const bf16x8* Wv = (const bf16x8*)Ws;
#pragma unroll
        for (int kk = 0; kk < 2; ++kk) {
            int sg = (kk * 4 + q) ^ (r15 & 7);
            bf16x8 af[4], bw[4];
#pragma unroll
            for (int ft = 0; ft < 4; ++ft)
                af[ft] = Xv[(wy * 64 + ft * 16 + r15) * 8 + sg];
#pragma unroll
            for (int fj = 0; fj < 4; ++fj)
                bw[fj] = Wv[(wx * 64 + fj * 16 + r15) * 8 + sg];
#pragma unroll
            for (int ft = 0; ft < 4; ++ft)
#pragma unroll
                for (int fj = 0; fj < 4; ++fj)
                    acc[ft][fj] = __builtin_amdgcn_mfma_f32_16x16x32_bf16(
                        af[ft], bw[fj], acc[ft][fj], 0, 0, 0);
        }
    }

    // epilogue: D[(q*4+r)][r15] per 16x16 frag
#pragma unroll
    for (int ft = 0; ft < 4; ++ft) {
#pragma unroll
        for (int r = 0; r < 4; ++r) {
            int t = t0 + wy * 64 + ft * 16 + q * 4 + r;
            if (t < TGT) {
                size_t rowoff = ((size_t)(b * TGT + t)) * M;
#pragma unroll
                for (int fj = 0; fj < 4; ++fj) {
                    int m = m0 + wx * 64 + fj * 16 + r15;
                    float v = acc[ft][fj][r];
                    if (bias) v += bias[m];
                    if (RELU_OUT) v = fmaxf(v, 0.f);
                    if (OUT_BF16)
                        ((__hip_bfloat16*)Y)[rowoff + m] = __float2bfloat16(v);
                    else
                        ((float*)Y)[rowoff + m] = v;
                }
            }
        }
    }
}

// ============================================================
extern "C" void kernel_launch(void* const* d_in, const int* in_sizes, int n_in,
                              void* d_out, int out_size, void* d_ws, size_t ws_size,
                              hipStream_t stream)
{
    const float* inputs   = (const float*)d_in[0];
    const float* cond     = (const float*)d_in[1];
    const float* input_w  = (const float*)d_in[2];
    const float* filter_w = (const float*)d_in[3];
    const float* gate_w   = (const float*)d_in[4];
    const float* res_w    = (const float*)d_in[5];
    const float* split_w  = (const float*)d_in[6];
    const float* gcf_w    = (const float*)d_in[7];
    const float* gcs_w    = (const float*)d_in[8];
    const float* f1_w     = (const float*)d_in[9];
    const float* f1_b     = (const float*)d_in[10];
    const float* f2_w     = (const float*)d_in[11];
    const float* f2_b     = (const float*)d_in[12];
    float* out = (float*)d_out;

    char* wsb = (char*)d_ws;
    const size_t RES_B   = (size_t)Bc * RCc * Lc * 4;        // 2 MB each
    const size_t OUTS_B  = (size_t)Bc * TGT * KTOT * 2;      // 15.7 MB
    const size_t FIN_B   = (size_t)Bc * TGT * SCc * 2;       // 25.2 MB
    const size_t H1_B    = (size_t)Bc * TGT * ECc * 2;       // 12.6 MB
    const size_t W1_B    = (size_t)SCc * KTOT * 2;
    const size_t W2_B    = (size_t)ECc * SCc * 2;

    float* res0              = (float*)wsb;                   size_t off = RES_B;
    float* res1              = (float*)(wsb + off);           off += RES_B;
    __hip_bfloat16* outsT    = (__hip_bfloat16*)(wsb + off);  off += OUTS_B;
    __hip_bfloat16* finalT   = (__hip_bfloat16*)(wsb + off);  off += FIN_B;
    __hip_bfloat16* h1T      = (__hip_bfloat16*)(wsb + off);  off += H1_B;
    __hip_bfloat16* Wp1      = (__hip_bfloat16*)(wsb + off);  off += W1_B;
    __hip_bfloat16* Wp2      = (__hip_bfloat16*)(wsb + off);  off += W2_B;
    __hip_bfloat16* Wp3      = (__hip_bfloat16*)(wsb + off);

    // weight packs (independent of activations)
    pack_w1<<<(SCc * KTOT + 255) / 256, 256, 0, stream>>>(split_w, Wp1);
    pack_plain<<<(ECc * SCc + 255) / 256, 256, 0, stream>>>(f1_w, Wp2, ECc * SCc);
    pack_plain<<<(OCc * ECc + 255) / 256, 256, 0, stream>>>(f2_w, Wp3, OCc * ECc);

    input_conv<<<dim3(Lc / 64, Bc), 256, 0, stream>>>(inputs, input_w, res0);

    float* rin = res0;
    float* rout = res1;
    for (int i = 0; i < NL; ++i) {
        int d = 1 << (i % 10);
        layer_kernel<<<dim3(Lc / 64, Bc), 256, 0, stream>>>(
            rin, rout, outsT,
            filter_w + (size_t)i * DCc * RCc * 2,
            gate_w   + (size_t)i * DCc * RCc * 2,
            res_w    + (size_t)i * RCc * DCc,
            cond,
            gcf_w + i * 5,
            gcs_w + i * 5,
            d, i);
        float* tmp = rin; rin = rout; rout = tmp;
    }

    // G1: finalT = relu( outsT(12292x640) @ Wp1^T )   -> bf16 [t][1024]
    gemm_mfma<true, true><<<dim3(SCc / 128, Bc * TTILES), 256, 0, stream>>>(
        outsT, Wp1, nullptr, finalT, SCc, KTOT);

    // G2: h1T = relu( finalT @ Wp2^T + f1_b )         -> bf16 [t][512]
    gemm_mfma<true, true><<<dim3(ECc / 128, Bc * TTILES), 256, 0, stream>>>(
        finalT, Wp2, f1_b, h1T, ECc, SCc);

    // G3: out = h1T @ Wp3^T + f2_b                    -> fp32 [t][256] (final layout)
    gemm_mfma<false, false><<<dim3(OCc / 128, Bc * TTILES), 256, 0, stream>>>(
        h1T, Wp3, f2_b, out, OCc, ECc);
}